// Round 2
// baseline (322.786 us; speedup 1.0000x reference)
//
#include <hip/hip_runtime.h>
#include <math.h>

#define B_    32
#define S_    4096
#define DIN_  256
#define D_    256
#define T_    256
#define NB_   4
#define K_    5
#define EPS_  1e-5f
#define ROWS_ (B_ * T_)   // 8192

#define ORS_  16          // owned rows per block
#define CR_   32          // computed rows = owned + 8 halo each side
#define BR_   36          // buf0 rows = CR_ + 2 conv-pad rows each side
#define SEGS_ 16          // T_/ORS_
#define ASTR  264         // bf16 row stride in shorts (528 B, 16B-aligned)
#define HSTR  264         // h_lds row stride in floats (1056 B, 16B-aligned)

typedef short  shortx8 __attribute__((ext_vector_type(8)));
typedef float  floatx4 __attribute__((ext_vector_type(4)));

__device__ __forceinline__ unsigned short f2bf(float f) {
    unsigned int u = __float_as_uint(f);
    u += 0x7FFFu + ((u >> 16) & 1u);
    return (unsigned short)(u >> 16);
}
__device__ __forceinline__ unsigned int pack2bf(float a, float b) {
    return (unsigned int)f2bf(a) | ((unsigned int)f2bf(b) << 16);
}
__device__ __forceinline__ float bf2f_lo(unsigned int u) {
    return __uint_as_float(u << 16);
}
__device__ __forceinline__ float bf2f_hi(unsigned int u) {
    return __uint_as_float(u & 0xFFFF0000u);
}

// ---------------------------------------------------------------------------
// Setup: weight transpose+convert (z=0..8) and batch lengths (z=9).
// ---------------------------------------------------------------------------
__global__ void k_setup(const float* __restrict__ in_w, const float* __restrict__ win_w,
                        const float* __restrict__ wout_w, const unsigned int* __restrict__ mask_w,
                        unsigned short* __restrict__ wt_in, unsigned short* __restrict__ wt_win,
                        unsigned short* __restrict__ wt_wout, int* __restrict__ lengths) {
    int z = blockIdx.z;
    int tid = threadIdx.x;

    if (z == 9) {
        int b = blockIdx.y * 16 + blockIdx.x;
        if (b >= B_) return;
        int mode = 0;   // mask dtype detection (validated prior session)
        unsigned int w0 = mask_w[0];
        if (w0 == 0x3F800000u) mode = 2;
        else {
            bool u8 = false;
            for (int i = 0; i < 32; ++i)
                if (mask_w[i * 1024] > 1u) { u8 = true; break; }
            mode = u8 ? 1 : 0;
        }
        int s = 0;
        if (mode == 0) {
            const int* m = (const int*)mask_w;
            for (int i = tid; i < S_; i += 256) s += (m[(size_t)b * S_ + i] != 0);
        } else if (mode == 2) {
            const float* m = (const float*)mask_w;
            for (int i = tid; i < S_; i += 256) s += (m[(size_t)b * S_ + i] != 0.0f);
        } else {
            const unsigned char* m = (const unsigned char*)mask_w;
            for (int i = tid; i < S_; i += 256) s += (m[(size_t)b * S_ + i] != 0);
        }
        __shared__ int sm[256];
        sm[tid] = s;
        __syncthreads();
        for (int off = 128; off > 0; off >>= 1) {
            if (tid < off) sm[tid] += sm[tid + off];
            __syncthreads();
        }
        if (tid == 0) lengths[b] = sm[0];
        return;
    }

    const float* src; unsigned short* dst; int N, Kd;
    if (z == 0)      { src = in_w;                                   dst = wt_in;                                   N = D_;     Kd = DIN_; }
    else if (z <= 4) { src = win_w  + (size_t)(z - 1) * D_ * 2 * D_; dst = wt_win  + (size_t)(z - 1) * 2 * D_ * D_; N = 2 * D_; Kd = D_; }
    else             { src = wout_w + (size_t)(z - 5) * D_ * D_;     dst = wt_wout + (size_t)(z - 5) * D_ * D_;     N = D_;     Kd = D_; }
    int bx = blockIdx.x * 32;
    int by = blockIdx.y * 32;
    if (bx >= N) return;
    __shared__ float tile[32][33];
    int tx = tid & 31, ty = tid >> 5;
#pragma unroll
    for (int i = 0; i < 32; i += 8)
        tile[ty + i][tx] = src[(size_t)(by + ty + i) * N + bx + tx];
    __syncthreads();
#pragma unroll
    for (int i = 0; i < 32; i += 8)
        dst[(size_t)(bx + ty + i) * Kd + by + tx] = f2bf(tile[tx][ty + i]);
}

// ---------------------------------------------------------------------------
// Fully fused network: compress + in-proj + 4 conv blocks + final LN.
// One block per (batch, 16-row segment); 32 rows computed (8 halo/side),
// halo degrades 2 rows/side per layer -> owned 16 rows exact after 4 layers.
// h stays resident in LDS fp32; 69.7 KB LDS -> 2 blocks/CU (16 waves/CU)
// for cross-block latency hiding of the barrier-separated stage chain.
// VGPR budget: __launch_bounds__(512,4) caps at 128 regs; per-thread state
// minimized (no weight double-buffer; act fused into val-tile GEMM).
// ---------------------------------------------------------------------------
__global__ __launch_bounds__(512, 4) void k_fused(
    const float* __restrict__ x, const int* __restrict__ lengths,
    const unsigned short* __restrict__ wt_in, const float* __restrict__ in_b,
    const float* __restrict__ ln_g, const float* __restrict__ ln_b,
    const float* __restrict__ dw_w, const float* __restrict__ dw_b,
    const unsigned short* __restrict__ wt_win, const float* __restrict__ win_b,
    const unsigned short* __restrict__ wt_wout, const float* __restrict__ wout_b,
    const float* __restrict__ fn_g, const float* __restrict__ fn_b,
    float* __restrict__ out0, float* __restrict__ out1)
{
    __shared__ unsigned short buf0[BR_][ASTR];   // 19.0 KB: LN out / act
    __shared__ unsigned short buf1[CR_][ASTR];   // 16.9 KB: compressed x / conv out
    __shared__ float h_lds[CR_][HSTR];           // 33.8 KB: resident h (fp32)

    int tid = threadIdx.x;
    int w = tid >> 6, lane = tid & 63;
    int c16 = lane & 15, q = lane >> 4;
    int b = blockIdx.x >> 4, seg = blockIdx.x & (SEGS_ - 1);
    int t0 = seg * ORS_;
    // window row r in [0,32) corresponds to t = t0 - 8 + r

    // zero the conv pad rows of buf0 once (rows 0,1,34,35 never written again)
    if (tid < 132) {
        ((unsigned int*)buf0[0])[tid] = 0u;
        ((unsigned int*)buf0[1])[tid] = 0u;
        ((unsigned int*)buf0[BR_ - 2])[tid] = 0u;
        ((unsigned int*)buf0[BR_ - 1])[tid] = 0u;
    }

    int L = lengths[b];

    // ---- compress -> buf1 (bf16, 32 rows) ----
    {
        int tq = tid & 63, rg = tid >> 6;
        int col = tq * 4;
        float Lf = (float)L;
        float hi = fmaxf(Lf - 1.0f, 0.0f);
        int L1 = max(L - 1, 0);
        const float* xb = x + (size_t)b * S_ * DIN_ + col;
#pragma unroll
        for (int e = 0; e < 4; ++e) {
            int row = rg + e * 8;
            int t = t0 - 8 + row;
            t = min(max(t, 0), T_ - 1);          // out-of-range halo rows: garbage ok, masked at LN
            float src = ((float)t + 0.5f) * (Lf * (1.0f / T_)) - 0.5f;
            src = fminf(fmaxf(src, 0.0f), hi);
            int i0 = (int)floorf(src);
            int i1 = min(i0 + 1, L1);
            float wf = src - (float)i0;
            float4 v0 = *(const float4*)&xb[(size_t)i0 * DIN_];
            float4 v1 = *(const float4*)&xb[(size_t)i1 * DIN_];
            uint2 o;
            o.x = pack2bf((1.0f - wf) * v0.x + wf * v1.x, (1.0f - wf) * v0.y + wf * v1.y);
            o.y = pack2bf((1.0f - wf) * v0.z + wf * v1.z, (1.0f - wf) * v0.w + wf * v1.w);
            *(uint2*)&buf1[row][col] = o;
        }
    }
    __syncthreads();

    // ---- in-proj GEMM: buf1 (32x256) x wt_in -> h_lds fp32 ----
#pragma unroll
    for (int nn = 0; nn < 2; ++nn) {
        int nt = w + nn * 8;
        const unsigned short* wp = wt_in + (size_t)(nt * 16 + c16) * 256 + q * 8;
        shortx8 Bw[8];
#pragma unroll
        for (int kk = 0; kk < 8; ++kk) Bw[kk] = *(const shortx8*)(wp + kk * 32);
        floatx4 acc[2] = {};
#pragma unroll
        for (int kk = 0; kk < 8; ++kk)
#pragma unroll
            for (int mt = 0; mt < 2; ++mt) {
                shortx8 a = *(const shortx8*)&buf1[mt * 16 + c16][kk * 32 + q * 8];
                acc[mt] = __builtin_amdgcn_mfma_f32_16x16x32_bf16(a, Bw[kk], acc[mt], 0, 0, 0);
            }
        float obv = in_b[nt * 16 + c16];
#pragma unroll
        for (int mt = 0; mt < 2; ++mt)
#pragma unroll
            for (int r = 0; r < 4; ++r)
                h_lds[mt * 16 + q * 4 + r][nt * 16 + c16] = acc[mt][r] + obv;
    }
    __syncthreads();

    // ---- 4 conv blocks, h resident in LDS ----
    for (int li = 0; li < NB_; ++li) {
        const float* g_i = ln_g + li * D_;
        const float* b_i = ln_b + li * D_;
        const float* dww = dw_w + (size_t)li * D_ * K_;
        const float* dwb = dw_b + li * D_;
        const unsigned short* ww = wt_win + (size_t)li * 2 * D_ * D_;
        const float* wb = win_b + (size_t)li * 2 * D_;
        const unsigned short* ow = wt_wout + (size_t)li * D_ * D_;
        const float* obp = wout_b + li * D_;

        // ---- Stage A: LN h_lds -> buf0 rows 2..33 (bf16), zero out-of-range t ----
        {
            int c4 = lane * 4;
            float4 g4 = *(const float4*)&g_i[c4];
            float4 b4 = *(const float4*)&b_i[c4];
#pragma unroll
            for (int it = 0; it < 4; ++it) {
                int r = w + it * 8;
                float4 v = *(const float4*)&h_lds[r][c4];
                float s  = v.x + v.y + v.z + v.w;
                float ss = v.x * v.x + v.y * v.y + v.z * v.z + v.w * v.w;
#pragma unroll
                for (int off = 1; off < 64; off <<= 1) {
                    s += __shfl_xor(s, off);
                    ss += __shfl_xor(ss, off);
                }
                float mu = s * (1.0f / D_);
                float rsig = rsqrtf(ss * (1.0f / D_) - mu * mu + EPS_);
                uint2 o;
                o.x = pack2bf((v.x - mu) * rsig * g4.x + b4.x,
                              (v.y - mu) * rsig * g4.y + b4.y);
                o.y = pack2bf((v.z - mu) * rsig * g4.z + b4.z,
                              (v.w - mu) * rsig * g4.w + b4.w);
                int t = t0 - 8 + r;
                if (t < 0 || t >= T_) { o.x = 0; o.y = 0; }   // zero-padded conv boundary
                *(uint2*)&buf0[r + 2][c4] = o;
            }
        }
        __syncthreads();

        // ---- Stage B: depthwise conv buf0 -> buf1 (32 rows) ----
        {
            int tq = tid & 63, rg = tid >> 6;
            int col = tq * 4;
            float4 wk[K_];
#pragma unroll
            for (int k = 0; k < K_; ++k) {
                wk[k].x = dww[(col + 0) * K_ + k];
                wk[k].y = dww[(col + 1) * K_ + k];
                wk[k].z = dww[(col + 2) * K_ + k];
                wk[k].w = dww[(col + 3) * K_ + k];
            }
            float4 cb4 = *(const float4*)&dwb[col];
#pragma unroll
            for (int e = 0; e < 4; ++e) {
                int rr = rg + e * 8;
                float4 acc = cb4;
#pragma unroll
                for (int k = 0; k < K_; ++k) {
                    uint2 u = *(const uint2*)&buf0[rr + k][col];
                    acc.x += bf2f_lo(u.x) * wk[k].x;
                    acc.y += bf2f_hi(u.x) * wk[k].y;
                    acc.z += bf2f_lo(u.y) * wk[k].z;
                    acc.w += bf2f_hi(u.y) * wk[k].w;
                }
                uint2 o;
                o.x = pack2bf(acc.x, acc.y);
                o.y = pack2bf(acc.z, acc.w);
                *(uint2*)&buf1[rr][col] = o;
            }
        }
        __syncthreads();

        // ---- Stage C: win GEMM (32x512) + fused act -> buf0 rows 2..33 ----
        // nn=0,1 are gate tiles (kept in regs); nn=2,3 are val tiles: act is
        // applied immediately using the stored gate -> halves register state.
        float gvreg[2][2][4];
#pragma unroll
        for (int nn = 0; nn < 4; ++nn) {
            const unsigned short* wp = ww + (size_t)((w + nn * 8) * 16 + c16) * 256 + q * 8;
            shortx8 Bw[8];
#pragma unroll
            for (int kk = 0; kk < 8; ++kk) Bw[kk] = *(const shortx8*)(wp + kk * 32);
            floatx4 acc[2] = {};
#pragma unroll
            for (int kk = 0; kk < 8; ++kk)
#pragma unroll
                for (int mt = 0; mt < 2; ++mt) {
                    shortx8 a = *(const shortx8*)&buf1[mt * 16 + c16][kk * 32 + q * 8];
                    acc[mt] = __builtin_amdgcn_mfma_f32_16x16x32_bf16(a, Bw[kk], acc[mt], 0, 0, 0);
                }
            float bb = wb[(w + nn * 8) * 16 + c16];
            if (nn < 2) {
#pragma unroll
                for (int mt = 0; mt < 2; ++mt)
#pragma unroll
                    for (int r = 0; r < 4; ++r) gvreg[nn][mt][r] = acc[mt][r] + bb;
            } else {
                int pp = nn - 2;
                int colw = (w + pp * 8) * 16 + c16;
#pragma unroll
                for (int mt = 0; mt < 2; ++mt)
#pragma unroll
                    for (int r = 0; r < 4; ++r) {
                        float gate = gvreg[pp][mt][r];
                        float val  = acc[mt][r] + bb;
                        float sg = 1.0f / (1.0f + __expf(-gate));
                        float u = 1.5957691216f * (val + 0.044715f * val * val * val);
                        float ge = val / (1.0f + __expf(-u));
                        buf0[2 + mt * 16 + q * 4 + r][colw] = f2bf(sg * ge);
                    }
            }
        }
        __syncthreads();

        // ---- Stage D: wout GEMM + residual (h_lds update, disjoint per thread) ----
#pragma unroll
        for (int nn = 0; nn < 2; ++nn) {
            int nt = w + nn * 8;
            const unsigned short* wp = ow + (size_t)(nt * 16 + c16) * 256 + q * 8;
            shortx8 Bw[8];
#pragma unroll
            for (int kk = 0; kk < 8; ++kk) Bw[kk] = *(const shortx8*)(wp + kk * 32);
            floatx4 acc[2] = {};
#pragma unroll
            for (int kk = 0; kk < 8; ++kk)
#pragma unroll
                for (int mt = 0; mt < 2; ++mt) {
                    shortx8 a = *(const shortx8*)&buf0[2 + mt * 16 + c16][kk * 32 + q * 8];
                    acc[mt] = __builtin_amdgcn_mfma_f32_16x16x32_bf16(a, Bw[kk], acc[mt], 0, 0, 0);
                }
            float bb = obp[nt * 16 + c16];
#pragma unroll
            for (int mt = 0; mt < 2; ++mt)
#pragma unroll
                for (int r = 0; r < 4; ++r) {
                    int row = mt * 16 + q * 4 + r;
                    int col = nt * 16 + c16;
                    h_lds[row][col] = h_lds[row][col] + acc[mt][r] + bb;
                }
        }
        __syncthreads();
    }

    // ---- final LN on owned rows (8..23) -> out0; comp_mask -> out1 ----
    {
        int c4 = lane * 4;
        float4 g4 = *(const float4*)&fn_g[c4];
        float4 b4 = *(const float4*)&fn_b[c4];
#pragma unroll
        for (int it = 0; it < 2; ++it) {
            int r = 8 + w + it * 8;
            float4 v = *(const float4*)&h_lds[r][c4];
            float s  = v.x + v.y + v.z + v.w;
            float ss = v.x * v.x + v.y * v.y + v.z * v.z + v.w * v.w;
#pragma unroll
            for (int off = 1; off < 64; off <<= 1) {
                s += __shfl_xor(s, off);
                ss += __shfl_xor(ss, off);
            }
            float mu = s * (1.0f / D_);
            float rsig = rsqrtf(ss * (1.0f / D_) - mu * mu + EPS_);
            float4 o;
            o.x = (v.x - mu) * rsig * g4.x + b4.x;
            o.y = (v.y - mu) * rsig * g4.y + b4.y;
            o.z = (v.z - mu) * rsig * g4.z + b4.z;
            o.w = (v.w - mu) * rsig * g4.w + b4.w;
            *(float4*)&out0[((size_t)b * T_ + t0 + r - 8) * D_ + c4] = o;
        }
        if (tid < ORS_) out1[(size_t)b * T_ + t0 + tid] = 1.0f;
    }
}

// ---------------------------------------------------------------------------
extern "C" void kernel_launch(void* const* d_in, const int* in_sizes, int n_in,
                              void* d_out, int out_size, void* d_ws, size_t ws_size,
                              hipStream_t stream) {
    const float* x      = (const float*)d_in[0];
    const unsigned int* mask_w = (const unsigned int*)d_in[1];
    const float* in_w   = (const float*)d_in[2];
    const float* in_b   = (const float*)d_in[3];
    const float* ln_g   = (const float*)d_in[4];
    const float* ln_b   = (const float*)d_in[5];
    const float* dw_w   = (const float*)d_in[6];
    const float* dw_b   = (const float*)d_in[7];
    const float* win_w  = (const float*)d_in[8];
    const float* win_b  = (const float*)d_in[9];
    const float* wout_w = (const float*)d_in[10];
    const float* wout_b = (const float*)d_in[11];
    const float* fn_g   = (const float*)d_in[12];
    const float* fn_b   = (const float*)d_in[13];

    char* w8 = (char*)d_ws;
    unsigned short* wt_in   = (unsigned short*)w8;                 // 128 KB
    unsigned short* wt_win  = wt_in  + (size_t)D_ * DIN_;          // 1 MB
    unsigned short* wt_wout = wt_win + (size_t)NB_ * 2 * D_ * D_;  // 512 KB
    int* lengths = (int*)(w8 + (2u << 20));

    float* out0 = (float*)d_out;
    float* out1 = out0 + (size_t)ROWS_ * D_;

    k_setup<<<dim3(16, 8, 10), 256, 0, stream>>>(in_w, win_w, wout_w, mask_w,
                                                 wt_in, wt_win, wt_wout, lengths);
    k_fused<<<B_ * SEGS_, 512, 0, stream>>>(x, lengths, wt_in, in_b,
                                            ln_g, ln_b, dw_w, dw_b,
                                            wt_win, win_b, wt_wout, wout_b,
                                            fn_g, fn_b, out0, out1);
}